// Round 16
// baseline (168.083 us; speedup 1.0000x reference)
//
#include <hip/hip_runtime.h>
#include <hip/hip_bf16.h>

typedef __attribute__((ext_vector_type(4))) int i32x4;

#define TOK   4096
#define OUTF  4096
#define INF   4096
#define KE    4160   // 4096 main + 64 lora block (16 used + 48 zero) -> 65 K-tiles of 64
#define NT    65
#define RANKD 16

#define VMCNT(n) asm volatile("s_waitcnt vmcnt(" #n ")" ::: "memory")
#define SCHED0   __builtin_amdgcn_sched_barrier(0)
#define BAR      __builtin_amdgcn_s_barrier()

static __device__ __forceinline__ void gload_lds16(const void* g, void* l) {
  __builtin_amdgcn_global_load_lds(
      (const __attribute__((address_space(1))) void*)g,
      (__attribute__((address_space(3))) void*)l, 16, 0, 0);
}

static __device__ __forceinline__ unsigned int packq(float a, float b, float c, float d) {
  const int ia = (int)rintf(fminf(fmaxf(a, -127.f), 127.f));
  const int ib = (int)rintf(fminf(fmaxf(b, -127.f), 127.f));
  const int ic = (int)rintf(fminf(fmaxf(c, -127.f), 127.f));
  const int id = (int)rintf(fminf(fmaxf(d, -127.f), 127.f));
  return (ia & 255) | ((ib & 255) << 8) | ((ic & 255) << 16) | ((id & 255) << 24);
}

// ---- kernel 1 (reg-heavy, small): xA = x@A -> Xq lora cols + slx ----
__global__ __launch_bounds__(256) void k_xa(const float* __restrict__ x,
                                            const float* __restrict__ A,
                                            signed char* __restrict__ Xq,
                                            float* __restrict__ slx) {
  const int lane = threadIdx.x & 63;
  const int wave = threadIdx.x >> 6;
  const int m0 = blockIdx.x * 16 + wave * 4;
  float p[4][16];
#pragma unroll
  for (int a = 0; a < 4; ++a)
#pragma unroll
    for (int r = 0; r < 16; ++r) p[a][r] = 0.f;

  for (int k = lane; k < INF; k += 64) {
    const float4* a4 = (const float4*)&A[(size_t)k * RANKD];
    float av[16];
    *(float4*)&av[0]  = a4[0];
    *(float4*)&av[4]  = a4[1];
    *(float4*)&av[8]  = a4[2];
    *(float4*)&av[12] = a4[3];
#pragma unroll
    for (int rr = 0; rr < 4; ++rr) {
      const float xv = x[(size_t)(m0 + rr) * INF + k];
#pragma unroll
      for (int r = 0; r < 16; ++r) p[rr][r] = fmaf(xv, av[r], p[rr][r]);
    }
  }
#pragma unroll
  for (int rr = 0; rr < 4; ++rr)
#pragma unroll
    for (int r = 0; r < 16; ++r) {
      float v = p[rr][r];
      v += __shfl_xor(v, 1);  v += __shfl_xor(v, 2);
      v += __shfl_xor(v, 4);  v += __shfl_xor(v, 8);
      v += __shfl_xor(v, 16); v += __shfl_xor(v, 32);
      p[rr][r] = v;
    }
  if (lane == 0) {
#pragma unroll
    for (int rr = 0; rr < 4; ++rr) {
      float mx = 0.f;
#pragma unroll
      for (int r = 0; r < 16; ++r) mx = fmaxf(mx, fabsf(p[rr][r]));
      const float s = fmaxf(mx, 1e-30f) / 127.f;
      slx[m0 + rr] = s;
      const float inv = 1.f / s;
      signed char* dst = Xq + (size_t)(m0 + rr) * KE + INF;
      uint4 w;
      w.x = packq(p[rr][0] * inv,  p[rr][1] * inv,  p[rr][2] * inv,  p[rr][3] * inv);
      w.y = packq(p[rr][4] * inv,  p[rr][5] * inv,  p[rr][6] * inv,  p[rr][7] * inv);
      w.z = packq(p[rr][8] * inv,  p[rr][9] * inv,  p[rr][10] * inv, p[rr][11] * inv);
      w.w = packq(p[rr][12] * inv, p[rr][13] * inv, p[rr][14] * inv, p[rr][15] * inv);
      const uint4 z = {0u, 0u, 0u, 0u};
      *(uint4*)(dst + 0)  = w;
      *(uint4*)(dst + 16) = z;
      *(uint4*)(dst + 32) = z;
      *(uint4*)(dst + 48) = z;
    }
  }
}

// ---- kernel 2 (streaming, low-reg): blocks 0..1023 Wq; 1024..2047 Xq main ----
// Xq segment is two-pass (rowmax then reload+quantize; row stays L2-hot) to
// keep VGPR use low -> high occupancy -> BW-bound.
__global__ __launch_bounds__(256) void k_fill(const float* __restrict__ x,
                                              const int* __restrict__ q,
                                              const float* __restrict__ absmax,
                                              const float* __restrict__ cb,
                                              const float* __restrict__ B,
                                              signed char* __restrict__ Xq,
                                              signed char* __restrict__ Wq,
                                              float* __restrict__ sx,
                                              float* __restrict__ wr,
                                              float* __restrict__ sl) {
  const int lane = threadIdx.x & 63;
  const int wave = threadIdx.x >> 6;
  const int bid  = blockIdx.x;

  if (bid < 1024) {
    // ---------- Wq segment: 4 rows/block ----------
    __shared__ float cbs[16];
    if (threadIdx.x < 16) cbs[threadIdx.x] = cb[threadIdx.x];
    __syncthreads();
    const int o = bid * 4 + wave;
    float am = absmax[(size_t)o * 64 + lane];
    am = fmaxf(am, __shfl_xor(am, 1));  am = fmaxf(am, __shfl_xor(am, 2));
    am = fmaxf(am, __shfl_xor(am, 4));  am = fmaxf(am, __shfl_xor(am, 8));
    am = fmaxf(am, __shfl_xor(am, 16)); am = fmaxf(am, __shfl_xor(am, 32));
    const float amx = fmaxf(am, 1e-30f);
    const float qs  = 127.f / amx;
    if (lane == 0) wr[o] = amx / 127.f;
#pragma unroll
    for (int it = 0; it < 8; ++it) {
      const int k0 = it * 512 + lane * 8;
      const int4 q0 = *(const int4*)&q[(size_t)o * INF + k0];
      const int4 q1 = *(const int4*)&q[(size_t)o * INF + k0 + 4];
      const float f = absmax[(size_t)o * 64 + (k0 >> 6)] * qs;
      uint2 w;
      w.x = packq(cbs[q0.x] * f, cbs[q0.y] * f, cbs[q0.z] * f, cbs[q0.w] * f);
      w.y = packq(cbs[q1.x] * f, cbs[q1.y] * f, cbs[q1.z] * f, cbs[q1.w] * f);
      *(uint2*)&Wq[(size_t)o * KE + k0] = w;
    }
    const float bv = (lane < 16) ? B[(size_t)lane * OUTF + o] : 0.f;
    float ab = fabsf(bv);
    ab = fmaxf(ab, __shfl_xor(ab, 1)); ab = fmaxf(ab, __shfl_xor(ab, 2));
    ab = fmaxf(ab, __shfl_xor(ab, 4)); ab = fmaxf(ab, __shfl_xor(ab, 8));
    const float sB = fmaxf(ab, 1e-30f) / 127.f;   // valid on lanes 0..15
    if (lane == 0) sl[o] = 2.f * sB;              // lora scale (factor 2 = SCALING)
    signed char* dst = Wq + (size_t)o * KE + INF;
    if (lane < 16) dst[lane] = (signed char)(int)rintf(bv / sB);
    else dst[lane] = 0;
  } else {
    // ---------- Xq main segment: 4 rows/block, two-pass, low-reg ----------
    const int m = (bid - 1024) * 4 + wave;
    const float* xr = &x[(size_t)m * INF];
    float mx = 0.f;
#pragma unroll
    for (int it = 0; it < 16; ++it) {
      const float4 v = *(const float4*)&xr[it * 256 + lane * 4];
      mx = fmaxf(mx, fmaxf(fmaxf(fabsf(v.x), fabsf(v.y)),
                           fmaxf(fabsf(v.z), fabsf(v.w))));
    }
    mx = fmaxf(mx, __shfl_xor(mx, 1));  mx = fmaxf(mx, __shfl_xor(mx, 2));
    mx = fmaxf(mx, __shfl_xor(mx, 4));  mx = fmaxf(mx, __shfl_xor(mx, 8));
    mx = fmaxf(mx, __shfl_xor(mx, 16)); mx = fmaxf(mx, __shfl_xor(mx, 32));
    const float s = fmaxf(mx, 1e-30f) / 127.f;
    if (lane == 0) sx[m] = s;
    const float inv = 1.f / s;
#pragma unroll
    for (int it = 0; it < 16; ++it) {
      const float4 v = *(const float4*)&xr[it * 256 + lane * 4];
      const unsigned int w = packq(v.x * inv, v.y * inv, v.z * inv, v.w * inv);
      *(unsigned int*)&Xq[(size_t)m * KE + it * 256 + lane * 4] = w;
    }
  }
}

// ---------------- kernel 3: i8 GEMM (r14 verbatim) + dual-scale epilogue ----
// 256x256 tile, BK=64 (mfma_i32_16x16x64_i8), 8 waves (2Mx4N), ring-4 LDS
// (4 x 32KB = 128 KB): {read 12 frags(T); STAGE(T+2); 32 MFMA; vmcnt(4); bar}.
// out = sx[m]*wr[n]*main + slx[m]*sl[n]*lora + bias.
__global__ __launch_bounds__(512, 2) void k_gemm(const signed char* __restrict__ Xq,
                                                 const signed char* __restrict__ Wq,
                                                 const float* __restrict__ bias,
                                                 const float* __restrict__ sx,
                                                 const float* __restrict__ slx,
                                                 const float* __restrict__ wr,
                                                 const float* __restrict__ sl,
                                                 float* __restrict__ out) {
  extern __shared__ unsigned char LDS[];   // 4 slots x (A 16KB + B 16KB) = 128 KB
  const char* LB = (const char*)LDS;

  const int tid  = threadIdx.x;
  const int lane = tid & 63;
  const int wave = tid >> 6;        // 0..7
  const int waveM = wave >> 2;      // 0..1 -> rows [waveM*128, +128)
  const int waveN = wave & 3;       // 0..3 -> cols [waveN*64, +64)

  // XCD chunking: 256 wgs, 32 per XCD as 4 tile-rows x 8 tile-cols (bijective)
  const int wg   = blockIdx.x;
  const int xcd  = wg & 7;
  const int loc  = wg >> 3;
  const int trB  = ((xcd & 3) * 4 + (loc >> 3)) * 256;
  const int tcB  = ((xcd >> 2) * 8 + (loc & 7)) * 256;

  // ---- staging (linear LDS dest, pre-swizzled global source); rows = 64 B ----
  const int srow = lane >> 2;                                    // 0..15
  const int wb   = ((lane & 3) * 16) ^ (((lane >> 3) & 3) << 4); // byte in row
  const signed char* gA0 = Xq + (size_t)(trB + wave * 32 + srow) * KE + wb;
  const signed char* gA1 = gA0 + (size_t)16 * KE;
  const signed char* gB0 = Wq + (size_t)(tcB + wave * 32 + srow) * KE + wb;
  const signed char* gB1 = gB0 + (size_t)16 * KE;
  const int dA0 = wave * 2048;            // byte offsets within slot
  const int dA1 = wave * 2048 + 1024;
  const int dB0 = 16384 + wave * 2048;
  const int dB1 = 16384 + wave * 2048 + 1024;

  // ---- fragment reads: row=lane&15, k-quarter=(lane>>4)*16B, XOR swizzle ----
  const int fr   = lane & 15;
  const int kq16 = (lane >> 4) * 16;
  const int sw   = ((fr >> 1) & 3) << 4;
  const int aoff = (waveM * 128 + fr) * 64 + (kq16 ^ sw);
  const int boff = 16384 + (waveN * 64 + fr) * 64 + (kq16 ^ sw);

  i32x4 acc[8][4];
#pragma unroll
  for (int i = 0; i < 8; ++i)
#pragma unroll
    for (int j = 0; j < 4; ++j) acc[i][j] = i32x4{0, 0, 0, 0};

#define STAGE(t)                                                        \
  {                                                                     \
    const int sb_ = ((t) & 3) * 32768;                                  \
    const int k0_ = (t) * 64;                                           \
    gload_lds16(gA0 + k0_, LDS + sb_ + dA0);                            \
    gload_lds16(gA1 + k0_, LDS + sb_ + dA1);                            \
    gload_lds16(gB0 + k0_, LDS + sb_ + dB0);                            \
    gload_lds16(gB1 + k0_, LDS + sb_ + dB1);                            \
  }

  STAGE(0)
  STAGE(1)
  VMCNT(4);
  BAR; SCHED0;

  i32x4 a[8], b[4];

  for (int T = 0; T < NT - 2; ++T) {   // T = 0..62; stages up to tile 64
    const char* base = LB + (T & 3) * 32768;
#pragma unroll
    for (int i = 0; i < 8; ++i)
      a[i] = *(const i32x4*)(base + aoff + i * 1024);
#pragma unroll
    for (int j = 0; j < 4; ++j)
      b[j] = *(const i32x4*)(base + boff + j * 1024);
    STAGE(T + 2)
    __builtin_amdgcn_s_setprio(1);
#pragma unroll
    for (int i = 0; i < 8; ++i)
#pragma unroll
      for (int j = 0; j < 4; ++j)
        acc[i][j] = __builtin_amdgcn_mfma_i32_16x16x64_i8(a[i], b[j], acc[i][j], 0, 0, 0);
    __builtin_amdgcn_s_setprio(0);
    VMCNT(4);   // retire tile T+1's stage; T+2's stays in flight
    BAR; SCHED0;
  }

  // peel T = 63 (slot 3): last main tile; then publish tile 64
  {
    const char* base = LB + 3 * 32768;
#pragma unroll
    for (int i = 0; i < 8; ++i)
      a[i] = *(const i32x4*)(base + aoff + i * 1024);
#pragma unroll
    for (int j = 0; j < 4; ++j)
      b[j] = *(const i32x4*)(base + boff + j * 1024);
    __builtin_amdgcn_s_setprio(1);
#pragma unroll
    for (int i = 0; i < 8; ++i)
#pragma unroll
      for (int j = 0; j < 4; ++j)
        acc[i][j] = __builtin_amdgcn_mfma_i32_16x16x64_i8(a[i], b[j], acc[i][j], 0, 0, 0);
    __builtin_amdgcn_s_setprio(0);
    VMCNT(0);   // tile 64 (lora block, slot 0) landed
    BAR; SCHED0;
  }
#undef STAGE

  // ---- epilogue: lora tile 64 from slot 0 + dual-scale combine ----
  i32x4 aL[8], bL[4];
#pragma unroll
  for (int i = 0; i < 8; ++i)
    aL[i] = *(const i32x4*)(LB + aoff + i * 1024);
#pragma unroll
  for (int j = 0; j < 4; ++j)
    bL[j] = *(const i32x4*)(LB + boff + j * 1024);

  const int rq = (lane >> 4) * 4;
#pragma unroll
  for (int j = 0; j < 4; ++j) {
    const int n = tcB + waveN * 64 + j * 16 + fr;
    const float wrn = wr[n];
    const float sln = sl[n];
    const float bsn = bias[n];
#pragma unroll
    for (int i = 0; i < 8; ++i) {
      const i32x4 zz = {0, 0, 0, 0};
      const i32x4 t = __builtin_amdgcn_mfma_i32_16x16x64_i8(aL[i], bL[j], zz, 0, 0, 0);
      const int m0v = trB + waveM * 128 + i * 16 + rq;
      const float4 s4  = *(const float4*)&sx[m0v];
      const float4 sl4 = *(const float4*)&slx[m0v];
      const float* sp  = (const float*)&s4;
      const float* slp = (const float*)&sl4;
#pragma unroll
      for (int e = 0; e < 4; ++e) {
        const float v = (float)acc[i][j][e] * wrn * sp[e]
                      + (float)t[e] * sln * slp[e] + bsn;
        out[(size_t)(m0v + e) * OUTF + n] = v;
      }
    }
  }
}

extern "C" void kernel_launch(void* const* d_in, const int* in_sizes, int n_in,
                              void* d_out, int out_size, void* d_ws, size_t ws_size,
                              hipStream_t stream) {
  const float* x      = (const float*)d_in[0];
  const int*   q      = (const int*)d_in[1];
  const float* absmax = (const float*)d_in[2];
  const float* cb     = (const float*)d_in[3];
  const float* bias   = (const float*)d_in[4];
  const float* A      = (const float*)d_in[5];
  const float* B      = (const float*)d_in[6];
  float* out = (float*)d_out;

  signed char* Xq = (signed char*)d_ws;                       // 4096*4160 B
  signed char* Wq = Xq + (size_t)TOK * KE;                    // 4096*4160 B
  float* sx  = (float*)(Wq + (size_t)OUTF * KE);              // 4096 f32
  float* slx = sx + TOK;                                      // 4096 f32
  float* wr  = slx + TOK;                                     // 4096 f32
  float* sl  = wr + OUTF;                                     // 4096 f32

  hipFuncSetAttribute((const void*)k_gemm,
                      hipFuncAttributeMaxDynamicSharedMemorySize, 131072);

  k_xa<<<TOK / 16, 256, 0, stream>>>(x, A, Xq, slx);
  k_fill<<<2048, 256, 0, stream>>>(x, q, absmax, cb, B, Xq, Wq, sx, wr, sl);
  k_gemm<<<256, 512, 131072, stream>>>(Xq, Wq, bias, sx, slx, wr, sl, out);
}

// Round 17
// 137.677 us; speedup vs baseline: 1.2208x; 1.2208x over previous
//
#include <hip/hip_runtime.h>
#include <hip/hip_bf16.h>

typedef __attribute__((ext_vector_type(4))) int i32x4;

#define TOK   4096
#define OUTF  4096
#define INF   4096
#define KE    4160   // 4096 main + 64 lora block (16 used + 48 zero) -> 65 K-tiles of 64
#define NT    65
#define RANKD 16

#define VMCNT(n) asm volatile("s_waitcnt vmcnt(" #n ")" ::: "memory")
#define SCHED0   __builtin_amdgcn_sched_barrier(0)
#define BAR      __builtin_amdgcn_s_barrier()

static __device__ __forceinline__ void gload_lds16(const void* g, void* l) {
  __builtin_amdgcn_global_load_lds(
      (const __attribute__((address_space(1))) void*)g,
      (__attribute__((address_space(3))) void*)l, 16, 0, 0);
}

static __device__ __forceinline__ unsigned int packq(float a, float b, float c, float d) {
  const int ia = (int)rintf(fminf(fmaxf(a, -127.f), 127.f));
  const int ib = (int)rintf(fminf(fmaxf(b, -127.f), 127.f));
  const int ic = (int)rintf(fminf(fmaxf(c, -127.f), 127.f));
  const int id = (int)rintf(fminf(fmaxf(d, -127.f), 127.f));
  return (ia & 255) | ((ib & 255) << 8) | ((ic & 255) << 16) | ((id & 255) << 24);
}

// ---- kernel 1 (merged prep, 3 concurrent segments, one launch):
//   blocks    0..1023 : xA (K-split across 4 waves + LDS reduce) -> Xq lora cols + slx
//   blocks 1024..2047 : Wq = NF4 dequant-quantize (wr) + lora B cols (sl)
//   blocks 2048..3071 : Xq main = rint(x/sx), x row cached in regs
__global__ __launch_bounds__(256) void k_prep(const float* __restrict__ x,
                                              const float* __restrict__ A,
                                              const int* __restrict__ q,
                                              const float* __restrict__ absmax,
                                              const float* __restrict__ cb,
                                              const float* __restrict__ B,
                                              signed char* __restrict__ Xq,
                                              signed char* __restrict__ Wq,
                                              float* __restrict__ sx,
                                              float* __restrict__ slx,
                                              float* __restrict__ wr,
                                              float* __restrict__ sl) {
  const int lane = threadIdx.x & 63;
  const int wave = threadIdx.x >> 6;
  const int bid  = blockIdx.x;

  if (bid < 1024) {
    // ---------- xA segment: 4 rows/block, 4 waves K-split (1024 k each) ----------
    __shared__ float red[4][4][16];   // [wave][row][r]
    const int m0 = bid * 4;
    float p[4][16];
#pragma unroll
    for (int a = 0; a < 4; ++a)
#pragma unroll
      for (int r = 0; r < 16; ++r) p[a][r] = 0.f;

    const int kbase = wave * 1024;
#pragma unroll 2
    for (int it = 0; it < 16; ++it) {
      const int k = kbase + it * 64 + lane;
      const float4* a4 = (const float4*)&A[(size_t)k * RANKD];
      float av[16];
      *(float4*)&av[0]  = a4[0];
      *(float4*)&av[4]  = a4[1];
      *(float4*)&av[8]  = a4[2];
      *(float4*)&av[12] = a4[3];
#pragma unroll
      for (int rr = 0; rr < 4; ++rr) {
        const float xv = x[(size_t)(m0 + rr) * INF + k];
#pragma unroll
        for (int r = 0; r < 16; ++r) p[rr][r] = fmaf(xv, av[r], p[rr][r]);
      }
    }
#pragma unroll
    for (int rr = 0; rr < 4; ++rr)
#pragma unroll
      for (int r = 0; r < 16; ++r) {
        float v = p[rr][r];
        v += __shfl_xor(v, 1);  v += __shfl_xor(v, 2);
        v += __shfl_xor(v, 4);  v += __shfl_xor(v, 8);
        v += __shfl_xor(v, 16); v += __shfl_xor(v, 32);
        p[rr][r] = v;
      }
    if (lane == 0) {
#pragma unroll
      for (int rr = 0; rr < 4; ++rr)
#pragma unroll
        for (int r = 0; r < 16; ++r) red[wave][rr][r] = p[rr][r];
    }
    __syncthreads();
    if (wave == 0) {
      const int rr = lane >> 4;          // 0..3 (row)
      const int r  = lane & 15;          // 0..15
      float v = red[0][rr][r] + red[1][rr][r] + red[2][rr][r] + red[3][rr][r];
      float mx = fabsf(v);
      mx = fmaxf(mx, __shfl_xor(mx, 1));
      mx = fmaxf(mx, __shfl_xor(mx, 2));
      mx = fmaxf(mx, __shfl_xor(mx, 4));
      mx = fmaxf(mx, __shfl_xor(mx, 8));   // max over the 16-lane row group
      const float s = fmaxf(mx, 1e-30f) / 127.f;
      signed char* dst = Xq + (size_t)(m0 + rr) * KE + INF;
      const int iv = (int)rintf(fminf(fmaxf(v / s, -127.f), 127.f));
      dst[r] = (signed char)iv;
      if (r == 0) slx[m0 + rr] = s;
      if (r >= 1 && r <= 3) {            // zero pad bytes 16..63 of this row
        const uint4 z = {0u, 0u, 0u, 0u};
        *(uint4*)(dst + r * 16) = z;
      }
    }
  } else if (bid < 2048) {
    // ---------- Wq segment: 4 rows/block ----------
    __shared__ float cbs[16];
    if (threadIdx.x < 16) cbs[threadIdx.x] = cb[threadIdx.x];
    __syncthreads();
    const int o = (bid - 1024) * 4 + wave;
    float am = absmax[(size_t)o * 64 + lane];
    am = fmaxf(am, __shfl_xor(am, 1));  am = fmaxf(am, __shfl_xor(am, 2));
    am = fmaxf(am, __shfl_xor(am, 4));  am = fmaxf(am, __shfl_xor(am, 8));
    am = fmaxf(am, __shfl_xor(am, 16)); am = fmaxf(am, __shfl_xor(am, 32));
    const float amx = fmaxf(am, 1e-30f);
    const float qs  = 127.f / amx;
    if (lane == 0) wr[o] = amx / 127.f;
#pragma unroll
    for (int it = 0; it < 8; ++it) {
      const int k0 = it * 512 + lane * 8;
      const int4 q0 = *(const int4*)&q[(size_t)o * INF + k0];
      const int4 q1 = *(const int4*)&q[(size_t)o * INF + k0 + 4];
      const float f = absmax[(size_t)o * 64 + (k0 >> 6)] * qs;
      uint2 w;
      w.x = packq(cbs[q0.x] * f, cbs[q0.y] * f, cbs[q0.z] * f, cbs[q0.w] * f);
      w.y = packq(cbs[q1.x] * f, cbs[q1.y] * f, cbs[q1.z] * f, cbs[q1.w] * f);
      *(uint2*)&Wq[(size_t)o * KE + k0] = w;
    }
    const float bv = (lane < 16) ? B[(size_t)lane * OUTF + o] : 0.f;
    float ab = fabsf(bv);
    ab = fmaxf(ab, __shfl_xor(ab, 1)); ab = fmaxf(ab, __shfl_xor(ab, 2));
    ab = fmaxf(ab, __shfl_xor(ab, 4)); ab = fmaxf(ab, __shfl_xor(ab, 8));
    const float sB = fmaxf(ab, 1e-30f) / 127.f;   // valid on lanes 0..15
    if (lane == 0) sl[o] = 2.f * sB;              // lora scale (factor 2 = SCALING)
    signed char* dst = Wq + (size_t)o * KE + INF;
    if (lane < 16) dst[lane] = (signed char)(int)rintf(bv / sB);
    else dst[lane] = 0;
  } else {
    // ---------- Xq main segment: 4 rows/block, 1 row/wave, x cached in regs ----------
    const int m = (bid - 2048) * 4 + wave;
    float4 v[16];
    float mx = 0.f;
#pragma unroll
    for (int it = 0; it < 16; ++it) {
      v[it] = *(const float4*)&x[(size_t)m * INF + it * 256 + lane * 4];
      mx = fmaxf(mx, fmaxf(fmaxf(fabsf(v[it].x), fabsf(v[it].y)),
                           fmaxf(fabsf(v[it].z), fabsf(v[it].w))));
    }
    mx = fmaxf(mx, __shfl_xor(mx, 1));  mx = fmaxf(mx, __shfl_xor(mx, 2));
    mx = fmaxf(mx, __shfl_xor(mx, 4));  mx = fmaxf(mx, __shfl_xor(mx, 8));
    mx = fmaxf(mx, __shfl_xor(mx, 16)); mx = fmaxf(mx, __shfl_xor(mx, 32));
    const float s = fmaxf(mx, 1e-30f) / 127.f;
    if (lane == 0) sx[m] = s;
    const float inv = 1.f / s;
#pragma unroll
    for (int it = 0; it < 16; ++it) {
      const unsigned int w = packq(v[it].x * inv, v[it].y * inv,
                                   v[it].z * inv, v[it].w * inv);
      *(unsigned int*)&Xq[(size_t)m * KE + it * 256 + lane * 4] = w;
    }
  }
}

// ---------------- kernel 2: i8 GEMM (r14 verbatim) + dual-scale epilogue ----
// 256x256 tile, BK=64 (mfma_i32_16x16x64_i8), 8 waves (2Mx4N), ring-4 LDS
// (4 x 32KB = 128 KB): {read 12 frags(T); STAGE(T+2); 32 MFMA; vmcnt(4); bar}.
// out = sx[m]*wr[n]*main + slx[m]*sl[n]*lora + bias.
__global__ __launch_bounds__(512, 2) void k_gemm(const signed char* __restrict__ Xq,
                                                 const signed char* __restrict__ Wq,
                                                 const float* __restrict__ bias,
                                                 const float* __restrict__ sx,
                                                 const float* __restrict__ slx,
                                                 const float* __restrict__ wr,
                                                 const float* __restrict__ sl,
                                                 float* __restrict__ out) {
  extern __shared__ unsigned char LDS[];   // 4 slots x (A 16KB + B 16KB) = 128 KB
  const char* LB = (const char*)LDS;

  const int tid  = threadIdx.x;
  const int lane = tid & 63;
  const int wave = tid >> 6;        // 0..7
  const int waveM = wave >> 2;      // 0..1 -> rows [waveM*128, +128)
  const int waveN = wave & 3;       // 0..3 -> cols [waveN*64, +64)

  // XCD chunking: 256 wgs, 32 per XCD as 4 tile-rows x 8 tile-cols (bijective)
  const int wg   = blockIdx.x;
  const int xcd  = wg & 7;
  const int loc  = wg >> 3;
  const int trB  = ((xcd & 3) * 4 + (loc >> 3)) * 256;
  const int tcB  = ((xcd >> 2) * 8 + (loc & 7)) * 256;

  // ---- staging (linear LDS dest, pre-swizzled global source); rows = 64 B ----
  const int srow = lane >> 2;                                    // 0..15
  const int wb   = ((lane & 3) * 16) ^ (((lane >> 3) & 3) << 4); // byte in row
  const signed char* gA0 = Xq + (size_t)(trB + wave * 32 + srow) * KE + wb;
  const signed char* gA1 = gA0 + (size_t)16 * KE;
  const signed char* gB0 = Wq + (size_t)(tcB + wave * 32 + srow) * KE + wb;
  const signed char* gB1 = gB0 + (size_t)16 * KE;
  const int dA0 = wave * 2048;            // byte offsets within slot
  const int dA1 = wave * 2048 + 1024;
  const int dB0 = 16384 + wave * 2048;
  const int dB1 = 16384 + wave * 2048 + 1024;

  // ---- fragment reads: row=lane&15, k-quarter=(lane>>4)*16B, XOR swizzle ----
  const int fr   = lane & 15;
  const int kq16 = (lane >> 4) * 16;
  const int sw   = ((fr >> 1) & 3) << 4;
  const int aoff = (waveM * 128 + fr) * 64 + (kq16 ^ sw);
  const int boff = 16384 + (waveN * 64 + fr) * 64 + (kq16 ^ sw);

  i32x4 acc[8][4];
#pragma unroll
  for (int i = 0; i < 8; ++i)
#pragma unroll
    for (int j = 0; j < 4; ++j) acc[i][j] = i32x4{0, 0, 0, 0};

#define STAGE(t)                                                        \
  {                                                                     \
    const int sb_ = ((t) & 3) * 32768;                                  \
    const int k0_ = (t) * 64;                                           \
    gload_lds16(gA0 + k0_, LDS + sb_ + dA0);                            \
    gload_lds16(gA1 + k0_, LDS + sb_ + dA1);                            \
    gload_lds16(gB0 + k0_, LDS + sb_ + dB0);                            \
    gload_lds16(gB1 + k0_, LDS + sb_ + dB1);                            \
  }

  STAGE(0)
  STAGE(1)
  VMCNT(4);
  BAR; SCHED0;

  i32x4 a[8], b[4];

  for (int T = 0; T < NT - 2; ++T) {   // T = 0..62; stages up to tile 64
    const char* base = LB + (T & 3) * 32768;
#pragma unroll
    for (int i = 0; i < 8; ++i)
      a[i] = *(const i32x4*)(base + aoff + i * 1024);
#pragma unroll
    for (int j = 0; j < 4; ++j)
      b[j] = *(const i32x4*)(base + boff + j * 1024);
    STAGE(T + 2)
    __builtin_amdgcn_s_setprio(1);
#pragma unroll
    for (int i = 0; i < 8; ++i)
#pragma unroll
      for (int j = 0; j < 4; ++j)
        acc[i][j] = __builtin_amdgcn_mfma_i32_16x16x64_i8(a[i], b[j], acc[i][j], 0, 0, 0);
    __builtin_amdgcn_s_setprio(0);
    VMCNT(4);   // retire tile T+1's stage; T+2's stays in flight
    BAR; SCHED0;
  }

  // peel T = 63 (slot 3): last main tile; then publish tile 64
  {
    const char* base = LB + 3 * 32768;
#pragma unroll
    for (int i = 0; i < 8; ++i)
      a[i] = *(const i32x4*)(base + aoff + i * 1024);
#pragma unroll
    for (int j = 0; j < 4; ++j)
      b[j] = *(const i32x4*)(base + boff + j * 1024);
    __builtin_amdgcn_s_setprio(1);
#pragma unroll
    for (int i = 0; i < 8; ++i)
#pragma unroll
      for (int j = 0; j < 4; ++j)
        acc[i][j] = __builtin_amdgcn_mfma_i32_16x16x64_i8(a[i], b[j], acc[i][j], 0, 0, 0);
    __builtin_amdgcn_s_setprio(0);
    VMCNT(0);   // tile 64 (lora block, slot 0) landed
    BAR; SCHED0;
  }
#undef STAGE

  // ---- epilogue: lora tile 64 from slot 0 + dual-scale combine ----
  i32x4 aL[8], bL[4];
#pragma unroll
  for (int i = 0; i < 8; ++i)
    aL[i] = *(const i32x4*)(LB + aoff + i * 1024);
#pragma unroll
  for (int j = 0; j < 4; ++j)
    bL[j] = *(const i32x4*)(LB + boff + j * 1024);

  const int rq = (lane >> 4) * 4;
#pragma unroll
  for (int j = 0; j < 4; ++j) {
    const int n = tcB + waveN * 64 + j * 16 + fr;
    const float wrn = wr[n];
    const float sln = sl[n];
    const float bsn = bias[n];
#pragma unroll
    for (int i = 0; i < 8; ++i) {
      const i32x4 zz = {0, 0, 0, 0};
      const i32x4 t = __builtin_amdgcn_mfma_i32_16x16x64_i8(aL[i], bL[j], zz, 0, 0, 0);
      const int m0v = trB + waveM * 128 + i * 16 + rq;
      const float4 s4  = *(const float4*)&sx[m0v];
      const float4 sl4 = *(const float4*)&slx[m0v];
      const float* sp  = (const float*)&s4;
      const float* slp = (const float*)&sl4;
#pragma unroll
      for (int e = 0; e < 4; ++e) {
        const float v = (float)acc[i][j][e] * wrn * sp[e]
                      + (float)t[e] * sln * slp[e] + bsn;
        out[(size_t)(m0v + e) * OUTF + n] = v;
      }
    }
  }
}

extern "C" void kernel_launch(void* const* d_in, const int* in_sizes, int n_in,
                              void* d_out, int out_size, void* d_ws, size_t ws_size,
                              hipStream_t stream) {
  const float* x      = (const float*)d_in[0];
  const int*   q      = (const int*)d_in[1];
  const float* absmax = (const float*)d_in[2];
  const float* cb     = (const float*)d_in[3];
  const float* bias   = (const float*)d_in[4];
  const float* A      = (const float*)d_in[5];
  const float* B      = (const float*)d_in[6];
  float* out = (float*)d_out;

  signed char* Xq = (signed char*)d_ws;                       // 4096*4160 B
  signed char* Wq = Xq + (size_t)TOK * KE;                    // 4096*4160 B
  float* sx  = (float*)(Wq + (size_t)OUTF * KE);              // 4096 f32
  float* slx = sx + TOK;                                      // 4096 f32
  float* wr  = slx + TOK;                                     // 4096 f32
  float* sl  = wr + OUTF;                                     // 4096 f32

  hipFuncSetAttribute((const void*)k_gemm,
                      hipFuncAttributeMaxDynamicSharedMemorySize, 131072);

  k_prep<<<3072, 256, 0, stream>>>(x, A, q, absmax, cb, B, Xq, Wq, sx, slx, wr, sl);
  k_gemm<<<256, 512, 131072, stream>>>(Xq, Wq, bias, sx, slx, wr, sl, out);
}

// Round 18
// 134.893 us; speedup vs baseline: 1.2460x; 1.0206x over previous
//
#include <hip/hip_runtime.h>
#include <hip/hip_bf16.h>

typedef __attribute__((ext_vector_type(4))) int i32x4;

#define TOK   4096
#define OUTF  4096
#define INF   4096
#define KE    4160   // 4096 main + 64 lora block (16 used + 48 zero) -> 65 K-tiles of 64
#define NT    65
#define RANKD 16

#define VMCNT(n) asm volatile("s_waitcnt vmcnt(" #n ")" ::: "memory")
#define SCHED0   __builtin_amdgcn_sched_barrier(0)
#define BAR      __builtin_amdgcn_s_barrier()

static __device__ __forceinline__ void gload_lds16(const void* g, void* l) {
  __builtin_amdgcn_global_load_lds(
      (const __attribute__((address_space(1))) void*)g,
      (__attribute__((address_space(3))) void*)l, 16, 0, 0);
}

static __device__ __forceinline__ unsigned int packq(float a, float b, float c, float d) {
  const int ia = (int)rintf(fminf(fmaxf(a, -127.f), 127.f));
  const int ib = (int)rintf(fminf(fmaxf(b, -127.f), 127.f));
  const int ic = (int)rintf(fminf(fmaxf(c, -127.f), 127.f));
  const int id = (int)rintf(fminf(fmaxf(d, -127.f), 127.f));
  return (ia & 255) | ((ib & 255) << 8) | ((ic & 255) << 16) | ((id & 255) << 24);
}

// ---- kernel 1 (merged prep, 2 segments, one launch):
//   blocks    0..1023 : x-segment — 4 rows/block, 4 waves K-split.
//     pass1: xA partial FMA + partial row-absmax (one x HBM read).
//     LDS reduce -> wave0 writes lora cols + slx; all waves write sx + quantize
//     their K-quarter from L2-hot re-reads (no second HBM x pass).
//   blocks 1024..2047 : Wq = NF4 dequant-quantize (wr) + lora B cols (sl)
__global__ __launch_bounds__(256) void k_prep(const float* __restrict__ x,
                                              const float* __restrict__ A,
                                              const int* __restrict__ q,
                                              const float* __restrict__ absmax,
                                              const float* __restrict__ cb,
                                              const float* __restrict__ B,
                                              signed char* __restrict__ Xq,
                                              signed char* __restrict__ Wq,
                                              float* __restrict__ sx,
                                              float* __restrict__ slx,
                                              float* __restrict__ wr,
                                              float* __restrict__ sl) {
  const int lane = threadIdx.x & 63;
  const int wave = threadIdx.x >> 6;
  const int bid  = blockIdx.x;

  if (bid < 1024) {
    // ---------- x segment: 4 rows/block, 4 waves K-split (1024 k each) ----------
    __shared__ float red[4][4][16];    // [wave][row][r] xA partials
    __shared__ float redmx[4][4];      // [wave][row] partial row-absmax
    const int m0 = bid * 4;
    float p[4][16];
    float mxw[4] = {0.f, 0.f, 0.f, 0.f};
#pragma unroll
    for (int a = 0; a < 4; ++a)
#pragma unroll
      for (int r = 0; r < 16; ++r) p[a][r] = 0.f;

    const int kbase = wave * 1024;
#pragma unroll 2
    for (int it = 0; it < 16; ++it) {
      const int k = kbase + it * 64 + lane;
      const float4* a4 = (const float4*)&A[(size_t)k * RANKD];
      float av[16];
      *(float4*)&av[0]  = a4[0];
      *(float4*)&av[4]  = a4[1];
      *(float4*)&av[8]  = a4[2];
      *(float4*)&av[12] = a4[3];
#pragma unroll
      for (int rr = 0; rr < 4; ++rr) {
        const float xv = x[(size_t)(m0 + rr) * INF + k];
        mxw[rr] = fmaxf(mxw[rr], fabsf(xv));
#pragma unroll
        for (int r = 0; r < 16; ++r) p[rr][r] = fmaf(xv, av[r], p[rr][r]);
      }
    }
#pragma unroll
    for (int rr = 0; rr < 4; ++rr) {
#pragma unroll
      for (int r = 0; r < 16; ++r) {
        float v = p[rr][r];
        v += __shfl_xor(v, 1);  v += __shfl_xor(v, 2);
        v += __shfl_xor(v, 4);  v += __shfl_xor(v, 8);
        v += __shfl_xor(v, 16); v += __shfl_xor(v, 32);
        p[rr][r] = v;
      }
      float m = mxw[rr];
      m = fmaxf(m, __shfl_xor(m, 1));  m = fmaxf(m, __shfl_xor(m, 2));
      m = fmaxf(m, __shfl_xor(m, 4));  m = fmaxf(m, __shfl_xor(m, 8));
      m = fmaxf(m, __shfl_xor(m, 16)); m = fmaxf(m, __shfl_xor(m, 32));
      mxw[rr] = m;
    }
    if (lane == 0) {
#pragma unroll
      for (int rr = 0; rr < 4; ++rr) {
#pragma unroll
        for (int r = 0; r < 16; ++r) red[wave][rr][r] = p[rr][r];
        redmx[wave][rr] = mxw[rr];
      }
    }
    __syncthreads();
    // wave 0: lora cols (xA sum across waves) + slx, exactly as r17
    if (wave == 0) {
      const int rr = lane >> 4;          // 0..3 (row)
      const int r  = lane & 15;          // 0..15
      float v = red[0][rr][r] + red[1][rr][r] + red[2][rr][r] + red[3][rr][r];
      float mx = fabsf(v);
      mx = fmaxf(mx, __shfl_xor(mx, 1));
      mx = fmaxf(mx, __shfl_xor(mx, 2));
      mx = fmaxf(mx, __shfl_xor(mx, 4));
      mx = fmaxf(mx, __shfl_xor(mx, 8));   // max over the 16-lane row group
      const float s = fmaxf(mx, 1e-30f) / 127.f;
      signed char* dst = Xq + (size_t)(m0 + rr) * KE + INF;
      const int iv = (int)rintf(fminf(fmaxf(v / s, -127.f), 127.f));
      dst[r] = (signed char)iv;
      if (r == 0) slx[m0 + rr] = s;
      if (r >= 1 && r <= 3) {            // zero pad bytes 16..63 of this row
        const uint4 z = {0u, 0u, 0u, 0u};
        *(uint4*)(dst + r * 16) = z;
      }
    }
    // all waves: full rowmax -> sx; quantize own K-quarter (L2-hot re-read)
    float inv[4];
#pragma unroll
    for (int rr = 0; rr < 4; ++rr) {
      const float rm = fmaxf(fmaxf(redmx[0][rr], redmx[1][rr]),
                             fmaxf(redmx[2][rr], redmx[3][rr]));
      const float s = fmaxf(rm, 1e-30f) / 127.f;
      if (wave == 0 && lane == 0) sx[m0 + rr] = s;
      inv[rr] = 1.f / s;
    }
#pragma unroll
    for (int rr = 0; rr < 4; ++rr) {
#pragma unroll
      for (int it2 = 0; it2 < 4; ++it2) {
        const int k4 = kbase + it2 * 256 + lane * 4;
        const float4 v4 = *(const float4*)&x[(size_t)(m0 + rr) * INF + k4];
        const unsigned int w = packq(v4.x * inv[rr], v4.y * inv[rr],
                                     v4.z * inv[rr], v4.w * inv[rr]);
        *(unsigned int*)&Xq[(size_t)(m0 + rr) * KE + k4] = w;
      }
    }
  } else {
    // ---------- Wq segment: 4 rows/block ----------
    __shared__ float cbs[16];
    if (threadIdx.x < 16) cbs[threadIdx.x] = cb[threadIdx.x];
    __syncthreads();
    const int o = (bid - 1024) * 4 + wave;
    float am = absmax[(size_t)o * 64 + lane];
    am = fmaxf(am, __shfl_xor(am, 1));  am = fmaxf(am, __shfl_xor(am, 2));
    am = fmaxf(am, __shfl_xor(am, 4));  am = fmaxf(am, __shfl_xor(am, 8));
    am = fmaxf(am, __shfl_xor(am, 16)); am = fmaxf(am, __shfl_xor(am, 32));
    const float amx = fmaxf(am, 1e-30f);
    const float qs  = 127.f / amx;
    if (lane == 0) wr[o] = amx / 127.f;
#pragma unroll
    for (int it = 0; it < 8; ++it) {
      const int k0 = it * 512 + lane * 8;
      const int4 q0 = *(const int4*)&q[(size_t)o * INF + k0];
      const int4 q1 = *(const int4*)&q[(size_t)o * INF + k0 + 4];
      const float f = absmax[(size_t)o * 64 + (k0 >> 6)] * qs;
      uint2 w;
      w.x = packq(cbs[q0.x] * f, cbs[q0.y] * f, cbs[q0.z] * f, cbs[q0.w] * f);
      w.y = packq(cbs[q1.x] * f, cbs[q1.y] * f, cbs[q1.z] * f, cbs[q1.w] * f);
      *(uint2*)&Wq[(size_t)o * KE + k0] = w;
    }
    const float bv = (lane < 16) ? B[(size_t)lane * OUTF + o] : 0.f;
    float ab = fabsf(bv);
    ab = fmaxf(ab, __shfl_xor(ab, 1)); ab = fmaxf(ab, __shfl_xor(ab, 2));
    ab = fmaxf(ab, __shfl_xor(ab, 4)); ab = fmaxf(ab, __shfl_xor(ab, 8));
    const float sB = fmaxf(ab, 1e-30f) / 127.f;   // valid on lanes 0..15
    if (lane == 0) sl[o] = 2.f * sB;              // lora scale (factor 2 = SCALING)
    signed char* dst = Wq + (size_t)o * KE + INF;
    if (lane < 16) dst[lane] = (signed char)(int)rintf(bv / sB);
    else dst[lane] = 0;
  }
}

// ---------------- kernel 2: i8 GEMM (r14 verbatim) + dual-scale epilogue ----
// 256x256 tile, BK=64 (mfma_i32_16x16x64_i8), 8 waves (2Mx4N), ring-4 LDS
// (4 x 32KB = 128 KB): {read 12 frags(T); STAGE(T+2); 32 MFMA; vmcnt(4); bar}.
// out = sx[m]*wr[n]*main + slx[m]*sl[n]*lora + bias.
__global__ __launch_bounds__(512, 2) void k_gemm(const signed char* __restrict__ Xq,
                                                 const signed char* __restrict__ Wq,
                                                 const float* __restrict__ bias,
                                                 const float* __restrict__ sx,
                                                 const float* __restrict__ slx,
                                                 const float* __restrict__ wr,
                                                 const float* __restrict__ sl,
                                                 float* __restrict__ out) {
  extern __shared__ unsigned char LDS[];   // 4 slots x (A 16KB + B 16KB) = 128 KB
  const char* LB = (const char*)LDS;

  const int tid  = threadIdx.x;
  const int lane = tid & 63;
  const int wave = tid >> 6;        // 0..7
  const int waveM = wave >> 2;      // 0..1 -> rows [waveM*128, +128)
  const int waveN = wave & 3;       // 0..3 -> cols [waveN*64, +64)

  // XCD chunking: 256 wgs, 32 per XCD as 4 tile-rows x 8 tile-cols (bijective)
  const int wg   = blockIdx.x;
  const int xcd  = wg & 7;
  const int loc  = wg >> 3;
  const int trB  = ((xcd & 3) * 4 + (loc >> 3)) * 256;
  const int tcB  = ((xcd >> 2) * 8 + (loc & 7)) * 256;

  // ---- staging (linear LDS dest, pre-swizzled global source); rows = 64 B ----
  const int srow = lane >> 2;                                    // 0..15
  const int wb   = ((lane & 3) * 16) ^ (((lane >> 3) & 3) << 4); // byte in row
  const signed char* gA0 = Xq + (size_t)(trB + wave * 32 + srow) * KE + wb;
  const signed char* gA1 = gA0 + (size_t)16 * KE;
  const signed char* gB0 = Wq + (size_t)(tcB + wave * 32 + srow) * KE + wb;
  const signed char* gB1 = gB0 + (size_t)16 * KE;
  const int dA0 = wave * 2048;            // byte offsets within slot
  const int dA1 = wave * 2048 + 1024;
  const int dB0 = 16384 + wave * 2048;
  const int dB1 = 16384 + wave * 2048 + 1024;

  // ---- fragment reads: row=lane&15, k-quarter=(lane>>4)*16B, XOR swizzle ----
  const int fr   = lane & 15;
  const int kq16 = (lane >> 4) * 16;
  const int sw   = ((fr >> 1) & 3) << 4;
  const int aoff = (waveM * 128 + fr) * 64 + (kq16 ^ sw);
  const int boff = 16384 + (waveN * 64 + fr) * 64 + (kq16 ^ sw);

  i32x4 acc[8][4];
#pragma unroll
  for (int i = 0; i < 8; ++i)
#pragma unroll
    for (int j = 0; j < 4; ++j) acc[i][j] = i32x4{0, 0, 0, 0};

#define STAGE(t)                                                        \
  {                                                                     \
    const int sb_ = ((t) & 3) * 32768;                                  \
    const int k0_ = (t) * 64;                                           \
    gload_lds16(gA0 + k0_, LDS + sb_ + dA0);                            \
    gload_lds16(gA1 + k0_, LDS + sb_ + dA1);                            \
    gload_lds16(gB0 + k0_, LDS + sb_ + dB0);                            \
    gload_lds16(gB1 + k0_, LDS + sb_ + dB1);                            \
  }

  STAGE(0)
  STAGE(1)
  VMCNT(4);
  BAR; SCHED0;

  i32x4 a[8], b[4];

  for (int T = 0; T < NT - 2; ++T) {   // T = 0..62; stages up to tile 64
    const char* base = LB + (T & 3) * 32768;
#pragma unroll
    for (int i = 0; i < 8; ++i)
      a[i] = *(const i32x4*)(base + aoff + i * 1024);
#pragma unroll
    for (int j = 0; j < 4; ++j)
      b[j] = *(const i32x4*)(base + boff + j * 1024);
    STAGE(T + 2)
    __builtin_amdgcn_s_setprio(1);
#pragma unroll
    for (int i = 0; i < 8; ++i)
#pragma unroll
      for (int j = 0; j < 4; ++j)
        acc[i][j] = __builtin_amdgcn_mfma_i32_16x16x64_i8(a[i], b[j], acc[i][j], 0, 0, 0);
    __builtin_amdgcn_s_setprio(0);
    VMCNT(4);   // retire tile T+1's stage; T+2's stays in flight
    BAR; SCHED0;
  }

  // peel T = 63 (slot 3): last main tile; then publish tile 64
  {
    const char* base = LB + 3 * 32768;
#pragma unroll
    for (int i = 0; i < 8; ++i)
      a[i] = *(const i32x4*)(base + aoff + i * 1024);
#pragma unroll
    for (int j = 0; j < 4; ++j)
      b[j] = *(const i32x4*)(base + boff + j * 1024);
    __builtin_amdgcn_s_setprio(1);
#pragma unroll
    for (int i = 0; i < 8; ++i)
#pragma unroll
      for (int j = 0; j < 4; ++j)
        acc[i][j] = __builtin_amdgcn_mfma_i32_16x16x64_i8(a[i], b[j], acc[i][j], 0, 0, 0);
    __builtin_amdgcn_s_setprio(0);
    VMCNT(0);   // tile 64 (lora block, slot 0) landed
    BAR; SCHED0;
  }
#undef STAGE

  // ---- epilogue: lora tile 64 from slot 0 + dual-scale combine ----
  i32x4 aL[8], bL[4];
#pragma unroll
  for (int i = 0; i < 8; ++i)
    aL[i] = *(const i32x4*)(LB + aoff + i * 1024);
#pragma unroll
  for (int j = 0; j < 4; ++j)
    bL[j] = *(const i32x4*)(LB + boff + j * 1024);

  const int rq = (lane >> 4) * 4;
#pragma unroll
  for (int j = 0; j < 4; ++j) {
    const int n = tcB + waveN * 64 + j * 16 + fr;
    const float wrn = wr[n];
    const float sln = sl[n];
    const float bsn = bias[n];
#pragma unroll
    for (int i = 0; i < 8; ++i) {
      const i32x4 zz = {0, 0, 0, 0};
      const i32x4 t = __builtin_amdgcn_mfma_i32_16x16x64_i8(aL[i], bL[j], zz, 0, 0, 0);
      const int m0v = trB + waveM * 128 + i * 16 + rq;
      const float4 s4  = *(const float4*)&sx[m0v];
      const float4 sl4 = *(const float4*)&slx[m0v];
      const float* sp  = (const float*)&s4;
      const float* slp = (const float*)&sl4;
#pragma unroll
      for (int e = 0; e < 4; ++e) {
        const float v = (float)acc[i][j][e] * wrn * sp[e]
                      + (float)t[e] * sln * slp[e] + bsn;
        out[(size_t)(m0v + e) * OUTF + n] = v;
      }
    }
  }
}

extern "C" void kernel_launch(void* const* d_in, const int* in_sizes, int n_in,
                              void* d_out, int out_size, void* d_ws, size_t ws_size,
                              hipStream_t stream) {
  const float* x      = (const float*)d_in[0];
  const int*   q      = (const int*)d_in[1];
  const float* absmax = (const float*)d_in[2];
  const float* cb     = (const float*)d_in[3];
  const float* bias   = (const float*)d_in[4];
  const float* A      = (const float*)d_in[5];
  const float* B      = (const float*)d_in[6];
  float* out = (float*)d_out;

  signed char* Xq = (signed char*)d_ws;                       // 4096*4160 B
  signed char* Wq = Xq + (size_t)TOK * KE;                    // 4096*4160 B
  float* sx  = (float*)(Wq + (size_t)OUTF * KE);              // 4096 f32
  float* slx = sx + TOK;                                      // 4096 f32
  float* wr  = slx + TOK;                                     // 4096 f32
  float* sl  = wr + OUTF;                                     // 4096 f32

  hipFuncSetAttribute((const void*)k_gemm,
                      hipFuncAttributeMaxDynamicSharedMemorySize, 131072);

  k_prep<<<2048, 256, 0, stream>>>(x, A, q, absmax, cb, B, Xq, Wq, sx, slx, wr, sl);
  k_gemm<<<256, 512, 131072, stream>>>(Xq, Wq, bias, sx, slx, wr, sl, out);
}